// Round 1
// baseline (948.337 us; speedup 1.0000x reference)
//
#include <hip/hip_runtime.h>
#include <cstdint>
#include <cstddef>

// Problem constants
#define NBATCH 128
#define NTIME  512
#define NIN    64
#define NHID   256
#define NG     768     // 3*H
#define NLAT   32
#define NPp    16      // P
#define NPI    48
#define NOD    8
#define NPAR   1056
#define MEAN_OFF 0
#define STD_OFF  524288      // B*T*OD
#define HT_OFF   1048576     // 2*B*T*OD

typedef _Float16 f16;
typedef _Float16 f16x2 __attribute__((ext_vector_type(2)));

static __device__ __forceinline__ f16x2 u2h(uint32_t u) {
  union { uint32_t u; f16x2 h; } x; x.u = u; return x.h;
}

static __device__ __forceinline__ float fdot2(f16x2 a, f16x2 b, float c) {
#if __has_builtin(__builtin_amdgcn_fdot2)
  return __builtin_amdgcn_fdot2(a, b, c, false);   // v_dot2_f32_f16
#else
  return c + (float)a.x * (float)b.x + (float)a.y * (float)b.y;
#endif
}
static __device__ __forceinline__ float fexp2(float x) {
#if __has_builtin(__builtin_amdgcn_exp2f)
  return __builtin_amdgcn_exp2f(x);
#else
  return exp2f(x);
#endif
}
static __device__ __forceinline__ float frcp(float x) {
#if __has_builtin(__builtin_amdgcn_rcpf)
  return __builtin_amdgcn_rcpf(x);
#else
  return 1.0f / x;
#endif
}
static __device__ __forceinline__ float fsigmoid(float x) {
  return frcp(1.0f + fexp2(-1.4426950408889634f * x));
}
static __device__ __forceinline__ float ftanh(float x) {
  // tanh(x) = 1 - 2/(exp(2x)+1); saturates correctly at +/-inf
  return 1.0f - 2.0f * frcp(1.0f + fexp2(2.8853900817779268f * x));
}
static __device__ __forceinline__ float fexpf_(float x) {
  return fexp2(1.4426950408889634f * x);
}

// ---------------------------------------------------------------------------
// K1: gx[m, n] = sum_k x[m,k] * w_ih[n,k] + b_ih[n]   (M=65536, N=768, K=64)
// 64-row x 192-col tile per block, fp16 dot2, fp32 accum, fp16 output.
// ---------------------------------------------------------------------------
__global__ __launch_bounds__(256) void k_gx(
    const float* __restrict__ x, const float* __restrict__ w_ih,
    const float* __restrict__ b_ih, f16* __restrict__ gx)
{
  __shared__ f16x2 xs[64 * 33];    // padded leading dim: bank-conflict free
  __shared__ f16x2 ws[192 * 33];
  __shared__ float bs[192];
  const int tid = threadIdx.x;
  const int m0 = blockIdx.x * 64;
  const int c0 = blockIdx.y * 192;
  const float2* x2 = (const float2*)x;
  const float2* w2 = (const float2*)w_ih;
  for (int idx = tid; idx < 64 * 32; idx += 256) {
    int r = idx >> 5, kk = idx & 31;
    float2 v = x2[(size_t)(m0 + r) * 32 + kk];
    xs[r * 33 + kk] = f16x2{(f16)v.x, (f16)v.y};
  }
  for (int idx = tid; idx < 192 * 32; idx += 256) {
    int r = idx >> 5, kk = idx & 31;
    float2 v = w2[(size_t)(c0 + r) * 32 + kk];
    ws[r * 33 + kk] = f16x2{(f16)v.x, (f16)v.y};
  }
  if (tid < 192) bs[tid] = b_ih[c0 + tid];
  __syncthreads();

  const int tc = tid & 15;   // 16 col-groups x 12 cols  (lanes contiguous in cols)
  const int tr = tid >> 4;   // 16 row-groups x 4 rows
  float acc[4][12];
  #pragma unroll
  for (int j = 0; j < 4; ++j)
    #pragma unroll
    for (int i = 0; i < 12; ++i) acc[j][i] = 0.f;

  for (int kk = 0; kk < 32; ++kk) {
    f16x2 xa[4], wb[12];
    #pragma unroll
    for (int j = 0; j < 4; ++j) xa[j] = xs[(tr * 4 + j) * 33 + kk];
    #pragma unroll
    for (int i = 0; i < 12; ++i) wb[i] = ws[(tc * 12 + i) * 33 + kk];
    #pragma unroll
    for (int j = 0; j < 4; ++j)
      #pragma unroll
      for (int i = 0; i < 12; ++i) acc[j][i] = fdot2(xa[j], wb[i], acc[j][i]);
  }

  f16x2* g2 = (f16x2*)gx;
  #pragma unroll
  for (int j = 0; j < 4; ++j) {
    size_t row = (size_t)(m0 + tr * 4 + j);
    #pragma unroll
    for (int i2 = 0; i2 < 6; ++i2) {
      float a0 = acc[j][2 * i2]     + bs[tc * 12 + 2 * i2];
      float a1 = acc[j][2 * i2 + 1] + bs[tc * 12 + 2 * i2 + 1];
      g2[row * 384 + (size_t)(c0 / 2) + tc * 6 + i2] = f16x2{(f16)a0, (f16)a1};
    }
  }
}

// ---------------------------------------------------------------------------
// K2: GRU scan. One block (768 threads) per batch element; w_hh resident in
// VGPRs as fp16 (128 regs/thread). Per step: 128 v_dot2_f32_f16 per thread,
// h broadcast from LDS (wave-uniform kc -> conflict-free broadcast b128 reads),
// K-split-4 partials reduced through LDS, 256 threads finalize gates.
// ---------------------------------------------------------------------------
__global__ __launch_bounds__(768, 3) void k_scan(
    const float* __restrict__ hidden, const float* __restrict__ w_hh,
    const float* __restrict__ b_hh, const f16* __restrict__ gx,
    f16* __restrict__ rnn, float* __restrict__ out)
{
  __shared__ __align__(16) f16x2 h2[128];   // h as packed fp16 pairs
  __shared__ float hf[256];                 // h in fp32 (for update precision)
  __shared__ float parts[4 * 768];          // K-split partial sums
  __shared__ float bls[768];                // b_hh
  const int tid = threadIdx.x;
  const int b = blockIdx.x;
  const int wv = tid >> 6, lane = tid & 63;
  const int kc = wv & 3;                    // wave-uniform K-chunk (4 x 64)
  const int jb = (wv >> 2) * 64 + lane;     // 0..191

  // Stationary weights: rows {jb, jb+192, jb+384, jb+576}, k in [kc*64, kc*64+64)
  f16x2 wreg[4][32];
  const float2* wh2 = (const float2*)w_hh;
  #pragma unroll
  for (int r = 0; r < 4; ++r) {
    const int j = jb + 192 * r;
    #pragma unroll
    for (int c = 0; c < 32; ++c) {
      float2 v = wh2[(size_t)j * 128 + kc * 32 + c];
      wreg[r][c] = f16x2{(f16)v.x, (f16)v.y};
    }
  }
  bls[tid] = b_hh[tid];
  if (tid < 256) {
    float h0 = hidden[b * 256 + tid];
    hf[tid] = h0;
    ((f16*)h2)[tid] = (f16)h0;
  }
  __syncthreads();

  const uint4* hh4 = (const uint4*)h2;
  for (int t = 0; t < NTIME; ++t) {
    const size_t row = (size_t)b * NTIME + t;
    // prefetch gx for this step (hidden behind the dot phase)
    float gxr = 0.f, gxz = 0.f, gxn = 0.f;
    if (tid < 256) {
      const f16* g = gx + row * NG;
      gxr = (float)g[tid]; gxz = (float)g[256 + tid]; gxn = (float)g[512 + tid];
    }
    float a0 = 0.f, a1 = 0.f, a2 = 0.f, a3 = 0.f;
    #pragma unroll
    for (int c4 = 0; c4 < 8; ++c4) {
      uint4 hv = hh4[kc * 8 + c4];          // uniform address: broadcast
      f16x2 hx[4] = {u2h(hv.x), u2h(hv.y), u2h(hv.z), u2h(hv.w)};
      #pragma unroll
      for (int q = 0; q < 4; ++q) {
        a0 = fdot2(wreg[0][c4 * 4 + q], hx[q], a0);
        a1 = fdot2(wreg[1][c4 * 4 + q], hx[q], a1);
        a2 = fdot2(wreg[2][c4 * 4 + q], hx[q], a2);
        a3 = fdot2(wreg[3][c4 * 4 + q], hx[q], a3);
      }
    }
    parts[kc * 768 + jb]       = a0;
    parts[kc * 768 + jb + 192] = a1;
    parts[kc * 768 + jb + 384] = a2;
    parts[kc * 768 + jb + 576] = a3;
    __syncthreads();
    if (tid < 256) {
      float gr = bls[tid] + gxr;
      float gz = bls[256 + tid] + gxz;
      float hn = bls[512 + tid];
      #pragma unroll
      for (int c = 0; c < 4; ++c) {
        gr += parts[c * 768 + tid];
        gz += parts[c * 768 + 256 + tid];
        hn += parts[c * 768 + 512 + tid];
      }
      float r_ = fsigmoid(gr);
      float z_ = fsigmoid(gz);
      float n_ = ftanh(gxn + r_ * hn);
      float hnew = (1.0f - z_) * n_ + z_ * hf[tid];
      hf[tid] = hnew;
      ((f16*)h2)[tid] = (f16)hnew;
      rnn[row * NHID + tid] = (f16)hnew;
    }
    __syncthreads();
  }
  if (tid < 256) out[HT_OFF + b * 256 + tid] = hf[tid];
}

// ---------------------------------------------------------------------------
// K3 helper: 32-wide dot of one w_par row (fp16 in LDS, uniform broadcast)
// against te2 (fp16 pairs in regs), fp32 accum, 4 parallel chains.
// ---------------------------------------------------------------------------
static __device__ __forceinline__ float rowdot(const uint4* __restrict__ w4,
                                               const f16x2 te2[16],
                                               float init, int row)
{
  const uint4* p = w4 + row * 4;
  float a0 = init, a1 = 0.f, a2 = 0.f, a3 = 0.f;
  #pragma unroll
  for (int c4 = 0; c4 < 4; ++c4) {
    uint4 v = p[c4];
    a0 = fdot2(u2h(v.x), te2[4 * c4 + 0], a0);
    a1 = fdot2(u2h(v.y), te2[4 * c4 + 1], a1);
    a2 = fdot2(u2h(v.z), te2[4 * c4 + 2], a2);
    a3 = fdot2(u2h(v.w), te2[4 * c4 + 3], a3);
  }
  return (a0 + a1) + (a2 + a3);
}

// ---------------------------------------------------------------------------
// K3: head. One thread per (b,t) row (256 blocks x 256 threads = 65536).
// All weight reads are wave-uniform LDS broadcasts. LDS buffer is reused in
// 3 phases (w_lat / w_par[0:784) / w_par[784:1056)) to stay under 64 KB.
// ---------------------------------------------------------------------------
__global__ __launch_bounds__(256) void k_head(
    const float* __restrict__ x, const float* __restrict__ w_lat,
    const float* __restrict__ b_lat, const float* __restrict__ w_par,
    const float* __restrict__ b_par, const f16* __restrict__ rnn,
    float* __restrict__ out)
{
  __shared__ __align__(16) f16x2 buf[784 * 16];   // 50,176 B, reused per phase
  __shared__ float bpar_s[NPAR];
  __shared__ float blat_s[NLAT];
  const int tid = threadIdx.x;
  for (int idx = tid; idx < NPAR; idx += 256) bpar_s[idx] = b_par[idx];
  if (tid < NLAT) blat_s[tid] = b_lat[tid];

  // phase 0: w_lat (32 x 256) as fp16 pairs
  const float2* wl2 = (const float2*)w_lat;
  for (int idx = tid; idx < 32 * 128; idx += 256) {
    float2 v = wl2[idx];
    buf[idx] = f16x2{(f16)v.x, (f16)v.y};
  }
  __syncthreads();

  const size_t m = (size_t)blockIdx.x * 256 + tid;
  float te[32];
  #pragma unroll
  for (int c = 0; c < 32; ++c) te[c] = blat_s[c];
  const uint4* hrow = (const uint4*)(rnn + m * NHID);
  const uint4* wl4 = (const uint4*)buf;
  #pragma unroll 4
  for (int c4 = 0; c4 < 32; ++c4) {
    uint4 hv = hrow[c4];
    f16x2 hx0 = u2h(hv.x), hx1 = u2h(hv.y), hx2 = u2h(hv.z), hx3 = u2h(hv.w);
    #pragma unroll
    for (int c = 0; c < 32; ++c) {
      uint4 wv = wl4[c * 32 + c4];
      te[c] = fdot2(u2h(wv.x), hx0, te[c]);
      te[c] = fdot2(u2h(wv.y), hx1, te[c]);
      te[c] = fdot2(u2h(wv.z), hx2, te[c]);
      te[c] = fdot2(u2h(wv.w), hx3, te[c]);
    }
  }
  f16x2 te2[16];
  #pragma unroll
  for (int k = 0; k < 16; ++k) te2[k] = f16x2{(f16)te[2 * k], (f16)te[2 * k + 1]};
  __syncthreads();

  // phase 1: w_par rows [0, 784) = w_h (768) + b_h (16)
  const float2* wp2 = (const float2*)w_par;
  for (int idx = tid; idx < 784 * 16; idx += 256) {
    float2 v = wp2[idx];
    buf[idx] = f16x2{(f16)v.x, (f16)v.y};
  }
  __syncthreads();

  const uint4* wp4 = (const uint4*)buf;
  float vh[16];
  #pragma unroll
  for (int p = 0; p < 16; ++p) vh[p] = 0.f;
  for (int i = 0; i < NPI; ++i) {
    float xi = x[m * NIN + i];     // L1-resident after first touch
    #pragma unroll
    for (int p = 0; p < 16; ++p) {
      int row = p * NPI + i;
      float wv = rowdot(wp4, te2, bpar_s[row], row);
      vh[p] += wv * xi;
    }
  }
  float oh[16];
  #pragma unroll
  for (int p = 0; p < 16; ++p) {
    float bh = rowdot(wp4, te2, bpar_s[768 + p], 768 + p);
    oh[p] = ftanh(vh[p] + bh);
  }
  __syncthreads();

  // phase 2: w_par rows [784, 1056) = w_o (256) + b_o (16)
  for (int idx = tid; idx < 272 * 16; idx += 256) {
    float2 v = wp2[784 * 16 + idx];
    buf[idx] = f16x2{(f16)v.x, (f16)v.y};
  }
  __syncthreads();

  for (int o = 0; o < 16; ++o) {
    float macc = rowdot(wp4, te2, bpar_s[1040 + o], 256 + o);   // b_o[o]
    #pragma unroll
    for (int p = 0; p < 16; ++p) {
      int row = o * 16 + p;                                      // global 784+row
      float wv = rowdot(wp4, te2, bpar_s[784 + row], row);
      macc += wv * oh[p];
    }
    if (o < NOD) out[MEAN_OFF + m * NOD + o] = macc;
    else         out[STD_OFF + m * NOD + (o - NOD)] = fexpf_(macc);
  }
}

// ---------------------------------------------------------------------------
extern "C" void kernel_launch(void* const* d_in, const int* in_sizes, int n_in,
                              void* d_out, int out_size, void* d_ws, size_t ws_size,
                              hipStream_t stream)
{
  const float* x      = (const float*)d_in[0];
  const float* hidden = (const float*)d_in[1];
  const float* w_ih   = (const float*)d_in[2];
  const float* w_hh   = (const float*)d_in[3];
  const float* b_ih   = (const float*)d_in[4];
  const float* b_hh   = (const float*)d_in[5];
  const float* w_lat  = (const float*)d_in[6];
  const float* b_lat  = (const float*)d_in[7];
  const float* w_par  = (const float*)d_in[8];
  const float* b_par  = (const float*)d_in[9];
  float* out = (float*)d_out;

  f16* gx  = (f16*)d_ws;                                        // 100,663,296 B
  f16* rnn = (f16*)((char*)d_ws + (size_t)NBATCH * NTIME * NG * 2); // +33,554,432 B

  k_gx  <<<dim3(1024, 4), 256, 0, stream>>>(x, w_ih, b_ih, gx);
  k_scan<<<NBATCH, 768, 0, stream>>>(hidden, w_hh, b_hh, gx, rnn, out);
  k_head<<<256, 256, 0, stream>>>(x, w_lat, b_lat, w_par, b_par, rnn, out);
}

// Round 2
// 887.633 us; speedup vs baseline: 1.0684x; 1.0684x over previous
//
#include <hip/hip_runtime.h>
#include <cstdint>
#include <cstddef>

// Problem constants
#define NBATCH 128
#define NTIME  512
#define NIN    64
#define NHID   256
#define NG     768     // 3*H
#define NLAT   32
#define NPp    16      // P
#define NPI    48
#define NOD    8
#define NPAR   1056
#define MEAN_OFF 0
#define STD_OFF  524288      // B*T*OD
#define HT_OFF   1048576     // 2*B*T*OD

typedef _Float16 f16;
typedef _Float16 f16x2 __attribute__((ext_vector_type(2)));

static __device__ __forceinline__ f16x2 u2h(uint32_t u) {
  union { uint32_t u; f16x2 h; } x; x.u = u; return x.h;
}

static __device__ __forceinline__ float fdot2(f16x2 a, f16x2 b, float c) {
#if __has_builtin(__builtin_amdgcn_fdot2)
  return __builtin_amdgcn_fdot2(a, b, c, false);   // v_dot2_f32_f16
#else
  return c + (float)a.x * (float)b.x + (float)a.y * (float)b.y;
#endif
}
static __device__ __forceinline__ float fexp2(float x) {
#if __has_builtin(__builtin_amdgcn_exp2f)
  return __builtin_amdgcn_exp2f(x);
#else
  return exp2f(x);
#endif
}
static __device__ __forceinline__ float frcp(float x) {
#if __has_builtin(__builtin_amdgcn_rcpf)
  return __builtin_amdgcn_rcpf(x);
#else
  return 1.0f / x;
#endif
}
static __device__ __forceinline__ float fsigmoid(float x) {
  return frcp(1.0f + fexp2(-1.4426950408889634f * x));
}
static __device__ __forceinline__ float ftanh(float x) {
  return 1.0f - 2.0f * frcp(1.0f + fexp2(2.8853900817779268f * x));
}
static __device__ __forceinline__ float fexpf_(float x) {
  return fexp2(1.4426950408889634f * x);
}

// ---------------------------------------------------------------------------
// K1: gx[m, n] = sum_k x[m,k] * w_ih[n,k] + b_ih[n]   (M=65536, N=768, K=64)
// ---------------------------------------------------------------------------
__global__ __launch_bounds__(256) void k_gx(
    const float* __restrict__ x, const float* __restrict__ w_ih,
    const float* __restrict__ b_ih, f16* __restrict__ gx)
{
  __shared__ f16x2 xs[64 * 33];
  __shared__ f16x2 ws[192 * 33];
  __shared__ float bs[192];
  const int tid = threadIdx.x;
  const int m0 = blockIdx.x * 64;
  const int c0 = blockIdx.y * 192;
  const float2* x2 = (const float2*)x;
  const float2* w2 = (const float2*)w_ih;
  for (int idx = tid; idx < 64 * 32; idx += 256) {
    int r = idx >> 5, kk = idx & 31;
    float2 v = x2[(size_t)(m0 + r) * 32 + kk];
    xs[r * 33 + kk] = f16x2{(f16)v.x, (f16)v.y};
  }
  for (int idx = tid; idx < 192 * 32; idx += 256) {
    int r = idx >> 5, kk = idx & 31;
    float2 v = w2[(size_t)(c0 + r) * 32 + kk];
    ws[r * 33 + kk] = f16x2{(f16)v.x, (f16)v.y};
  }
  if (tid < 192) bs[tid] = b_ih[c0 + tid];
  __syncthreads();

  const int tc = tid & 15;
  const int tr = tid >> 4;
  float acc[4][12];
  #pragma unroll
  for (int j = 0; j < 4; ++j)
    #pragma unroll
    for (int i = 0; i < 12; ++i) acc[j][i] = 0.f;

  for (int kk = 0; kk < 32; ++kk) {
    f16x2 xa[4], wb[12];
    #pragma unroll
    for (int j = 0; j < 4; ++j) xa[j] = xs[(tr * 4 + j) * 33 + kk];
    #pragma unroll
    for (int i = 0; i < 12; ++i) wb[i] = ws[(tc * 12 + i) * 33 + kk];
    #pragma unroll
    for (int j = 0; j < 4; ++j)
      #pragma unroll
      for (int i = 0; i < 12; ++i) acc[j][i] = fdot2(xa[j], wb[i], acc[j][i]);
  }

  f16x2* g2 = (f16x2*)gx;
  #pragma unroll
  for (int j = 0; j < 4; ++j) {
    size_t row = (size_t)(m0 + tr * 4 + j);
    #pragma unroll
    for (int i2 = 0; i2 < 6; ++i2) {
      float a0 = acc[j][2 * i2]     + bs[tc * 12 + 2 * i2];
      float a1 = acc[j][2 * i2 + 1] + bs[tc * 12 + 2 * i2 + 1];
      g2[row * 384 + (size_t)(c0 / 2) + tc * 6 + i2] = f16x2{(f16)a0, (f16)a1};
    }
  }
}

// ---------------------------------------------------------------------------
// K2 v3: GRU scan. 512 threads/block, 1 batch/block, 128 blocks.
// Thread pair (2u,2u+1) owns unit u: all three gate rows (u, 256+u, 512+u),
// K split in half between the pair -> 3*64 = 192 f16x2 weight VGPRs/thread
// (fits the 256-reg cap at 2 waves/EU -> no AGPR/scratch pressure).
// K-reduce via shfl_xor(1) (no LDS parts); gate math on ALL waves
// (redundant per pair, but parallel); double-buffered h in LDS ->
// ONE barrier per step. gx prefetched 2 steps ahead.
// ---------------------------------------------------------------------------
__global__ __launch_bounds__(512, 2) void k_scan(
    const float* __restrict__ hidden, const float* __restrict__ w_hh,
    const float* __restrict__ b_hh, const f16* __restrict__ gx,
    f16* __restrict__ rnn, float* __restrict__ out)
{
  __shared__ __align__(16) f16x2 hbuf[2][128];   // double-buffered h (f16)
  const int tid = threadIdx.x;
  const int b = blockIdx.x;
  const int u  = tid >> 1;       // unit 0..255
  const int kh = tid & 1;        // k-half 0/1

  // --- stationary weights: rows u (r), 256+u (z), 512+u (n); k in [kh*128, kh*128+128)
  f16x2 wr[64], wz[64], wn[64];
  const float4* w4 = (const float4*)w_hh;   // 64 float4 per row
  #pragma unroll
  for (int c = 0; c < 32; ++c) {
    float4 v = w4[(size_t)u * 64 + kh * 32 + c];
    wr[2 * c]     = f16x2{(f16)v.x, (f16)v.y};
    wr[2 * c + 1] = f16x2{(f16)v.z, (f16)v.w};
  }
  #pragma unroll
  for (int c = 0; c < 32; ++c) {
    float4 v = w4[(size_t)(256 + u) * 64 + kh * 32 + c];
    wz[2 * c]     = f16x2{(f16)v.x, (f16)v.y};
    wz[2 * c + 1] = f16x2{(f16)v.z, (f16)v.w};
  }
  #pragma unroll
  for (int c = 0; c < 32; ++c) {
    float4 v = w4[(size_t)(512 + u) * 64 + kh * 32 + c];
    wn[2 * c]     = f16x2{(f16)v.x, (f16)v.y};
    wn[2 * c + 1] = f16x2{(f16)v.z, (f16)v.w};
  }
  const float br = b_hh[u];
  const float bz = b_hh[256 + u];
  const float bn = b_hh[512 + u];

  float hprev = hidden[b * 256 + u];
  if (tid < 256) ((f16*)hbuf[0])[tid] = (f16)hidden[b * 256 + tid];

  const f16* gp = gx + (size_t)b * NTIME * NG;
  // gx prefetch pipeline, depth 2
  f16 c_r = gp[u], c_z = gp[256 + u], c_n = gp[512 + u];
  f16 p_r = gp[NG + u], p_z = gp[NG + 256 + u], p_n = gp[NG + 512 + u];

  f16* rnn_p = rnn + (size_t)b * NTIME * NHID + u;
  __syncthreads();

  #pragma unroll 2
  for (int t = 0; t < NTIME; ++t) {
    // issue prefetch for t+2 (clamped; harmless reload at the tail)
    const int tpre = (t + 2 < NTIME) ? (t + 2) : (NTIME - 1);
    const f16* gq = gp + (size_t)tpre * NG;
    f16 q_r = gq[u], q_z = gq[256 + u], q_n = gq[512 + u];

    // --- dot phase: 192 v_dot2_f32_f16 per thread
    float a0 = 0.f, a1 = 0.f, b0 = 0.f, b1 = 0.f, d0 = 0.f, d1 = 0.f;
    const uint4* hb = (const uint4*)(&hbuf[t & 1][kh * 64]);
    #pragma unroll
    for (int c = 0; c < 16; ++c) {
      uint4 hv = hb[c];
      f16x2 h0 = u2h(hv.x), h1 = u2h(hv.y), h2v = u2h(hv.z), h3 = u2h(hv.w);
      a0 = fdot2(wr[4 * c + 0], h0, a0);
      a1 = fdot2(wr[4 * c + 1], h1, a1);
      b0 = fdot2(wz[4 * c + 0], h0, b0);
      b1 = fdot2(wz[4 * c + 1], h1, b1);
      d0 = fdot2(wn[4 * c + 0], h0, d0);
      d1 = fdot2(wn[4 * c + 1], h1, d1);
      a0 = fdot2(wr[4 * c + 2], h2v, a0);
      a1 = fdot2(wr[4 * c + 3], h3, a1);
      b0 = fdot2(wz[4 * c + 2], h2v, b0);
      b1 = fdot2(wz[4 * c + 3], h3, b1);
      d0 = fdot2(wn[4 * c + 2], h2v, d0);
      d1 = fdot2(wn[4 * c + 3], h3, d1);
    }
    float sr = a0 + a1, sz = b0 + b1, sn = d0 + d1;
    // pairwise K-reduce (lane ^ 1)
    sr += __shfl_xor(sr, 1, 64);
    sz += __shfl_xor(sz, 1, 64);
    sn += __shfl_xor(sn, 1, 64);

    // --- gates (both lanes of the pair compute identically)
    float gr = sr + br + (float)c_r;
    float gz = sz + bz + (float)c_z;
    float hn = sn + bn;
    float r_ = fsigmoid(gr);
    float z_ = fsigmoid(gz);
    float n_ = ftanh((float)c_n + r_ * hn);
    hprev = (1.0f - z_) * n_ + z_ * hprev;

    if (!kh) {
      ((f16*)hbuf[(t + 1) & 1])[u] = (f16)hprev;
      rnn_p[(size_t)t * NHID] = (f16)hprev;
    }
    // rotate gx pipeline
    c_r = p_r; c_z = p_z; c_n = p_n;
    p_r = q_r; p_z = q_z; p_n = q_n;
    __syncthreads();
  }
  if (!kh) out[HT_OFF + b * 256 + u] = hprev;
}

// ---------------------------------------------------------------------------
// K3 helper: 32-wide dot of one w_par row (fp16 in LDS, uniform broadcast)
// ---------------------------------------------------------------------------
static __device__ __forceinline__ float rowdot(const uint4* __restrict__ w4,
                                               const f16x2 te2[16],
                                               float init, int row)
{
  const uint4* p = w4 + row * 4;
  float a0 = init, a1 = 0.f, a2 = 0.f, a3 = 0.f;
  #pragma unroll
  for (int c4 = 0; c4 < 4; ++c4) {
    uint4 v = p[c4];
    a0 = fdot2(u2h(v.x), te2[4 * c4 + 0], a0);
    a1 = fdot2(u2h(v.y), te2[4 * c4 + 1], a1);
    a2 = fdot2(u2h(v.z), te2[4 * c4 + 2], a2);
    a3 = fdot2(u2h(v.w), te2[4 * c4 + 3], a3);
  }
  return (a0 + a1) + (a2 + a3);
}

// ---------------------------------------------------------------------------
// K3: head. 512 blocks x 128 threads (one (b,t) row per thread, full GPU).
// ---------------------------------------------------------------------------
#define HEAD_T 128
__global__ __launch_bounds__(HEAD_T) void k_head(
    const float* __restrict__ x, const float* __restrict__ w_lat,
    const float* __restrict__ b_lat, const float* __restrict__ w_par,
    const float* __restrict__ b_par, const f16* __restrict__ rnn,
    float* __restrict__ out)
{
  __shared__ __align__(16) f16x2 buf[784 * 16];   // 50,176 B, reused per phase
  __shared__ float bpar_s[NPAR];
  __shared__ float blat_s[NLAT];
  const int tid = threadIdx.x;
  for (int idx = tid; idx < NPAR; idx += HEAD_T) bpar_s[idx] = b_par[idx];
  if (tid < NLAT) blat_s[tid] = b_lat[tid];

  // phase 0: w_lat (32 x 256) as fp16 pairs
  const float2* wl2 = (const float2*)w_lat;
  for (int idx = tid; idx < 32 * 128; idx += HEAD_T) {
    float2 v = wl2[idx];
    buf[idx] = f16x2{(f16)v.x, (f16)v.y};
  }
  __syncthreads();

  const size_t m = (size_t)blockIdx.x * HEAD_T + tid;
  float te[32];
  #pragma unroll
  for (int c = 0; c < 32; ++c) te[c] = blat_s[c];
  const uint4* hrow = (const uint4*)(rnn + m * NHID);
  const uint4* wl4 = (const uint4*)buf;
  #pragma unroll 4
  for (int c4 = 0; c4 < 32; ++c4) {
    uint4 hv = hrow[c4];
    f16x2 hx0 = u2h(hv.x), hx1 = u2h(hv.y), hx2 = u2h(hv.z), hx3 = u2h(hv.w);
    #pragma unroll
    for (int c = 0; c < 32; ++c) {
      uint4 wv = wl4[c * 32 + c4];
      te[c] = fdot2(u2h(wv.x), hx0, te[c]);
      te[c] = fdot2(u2h(wv.y), hx1, te[c]);
      te[c] = fdot2(u2h(wv.z), hx2, te[c]);
      te[c] = fdot2(u2h(wv.w), hx3, te[c]);
    }
  }
  f16x2 te2[16];
  #pragma unroll
  for (int k = 0; k < 16; ++k) te2[k] = f16x2{(f16)te[2 * k], (f16)te[2 * k + 1]};
  __syncthreads();

  // phase 1: w_par rows [0, 784) = w_h (768) + b_h (16)
  const float2* wp2 = (const float2*)w_par;
  for (int idx = tid; idx < 784 * 16; idx += HEAD_T) {
    float2 v = wp2[idx];
    buf[idx] = f16x2{(f16)v.x, (f16)v.y};
  }
  __syncthreads();

  const uint4* wp4 = (const uint4*)buf;
  float vh[16];
  #pragma unroll
  for (int p = 0; p < 16; ++p) vh[p] = 0.f;
  for (int i = 0; i < NPI; ++i) {
    float xi = x[m * NIN + i];
    #pragma unroll
    for (int p = 0; p < 16; ++p) {
      int row = p * NPI + i;
      float wv = rowdot(wp4, te2, bpar_s[row], row);
      vh[p] += wv * xi;
    }
  }
  float oh[16];
  #pragma unroll
  for (int p = 0; p < 16; ++p) {
    float bh = rowdot(wp4, te2, bpar_s[768 + p], 768 + p);
    oh[p] = ftanh(vh[p] + bh);
  }
  __syncthreads();

  // phase 2: w_par rows [784, 1056) = w_o (256) + b_o (16)
  for (int idx = tid; idx < 272 * 16; idx += HEAD_T) {
    float2 v = wp2[784 * 16 + idx];
    buf[idx] = f16x2{(f16)v.x, (f16)v.y};
  }
  __syncthreads();

  for (int o = 0; o < 16; ++o) {
    float macc = rowdot(wp4, te2, bpar_s[1040 + o], 256 + o);   // b_o[o]
    #pragma unroll
    for (int p = 0; p < 16; ++p) {
      int row = o * 16 + p;
      float wv = rowdot(wp4, te2, bpar_s[784 + row], row);
      macc += wv * oh[p];
    }
    if (o < NOD) out[MEAN_OFF + m * NOD + o] = macc;
    else         out[STD_OFF + m * NOD + (o - NOD)] = fexpf_(macc);
  }
}

// ---------------------------------------------------------------------------
extern "C" void kernel_launch(void* const* d_in, const int* in_sizes, int n_in,
                              void* d_out, int out_size, void* d_ws, size_t ws_size,
                              hipStream_t stream)
{
  const float* x      = (const float*)d_in[0];
  const float* hidden = (const float*)d_in[1];
  const float* w_ih   = (const float*)d_in[2];
  const float* w_hh   = (const float*)d_in[3];
  const float* b_ih   = (const float*)d_in[4];
  const float* b_hh   = (const float*)d_in[5];
  const float* w_lat  = (const float*)d_in[6];
  const float* b_lat  = (const float*)d_in[7];
  const float* w_par  = (const float*)d_in[8];
  const float* b_par  = (const float*)d_in[9];
  float* out = (float*)d_out;

  f16* gx  = (f16*)d_ws;
  f16* rnn = (f16*)((char*)d_ws + (size_t)NBATCH * NTIME * NG * 2);

  k_gx  <<<dim3(1024, 4), 256, 0, stream>>>(x, w_ih, b_ih, gx);
  k_scan<<<NBATCH, 512, 0, stream>>>(hidden, w_hh, b_hh, gx, rnn, out);
  k_head<<<512, HEAD_T, 0, stream>>>(x, w_lat, b_lat, w_par, b_par, rnn, out);
}